// Round 1
// baseline (476.491 us; speedup 1.0000x reference)
//
#include <hip/hip_runtime.h>

// PersonaGNN: 2-layer GAT, N=100000 nodes, E=600000 edges (+ self loops),
// all dims 128, fp32 in/out, edge_index int32 [2][E].
//
// Pipeline per launch (all on `stream`):
//   CSR build over dst:  hist -> scan_a/b/c -> scatter      (rebuilt every call; ws is re-poisoned)
//   layer 1: gemm128(x,W1)->bufA; dots->vas/vad; gat_agg(relu)->bufB
//   layer 2: gemm128(bufB,W2)->bufA; dots; gat_agg->bufB
//   mean over nodes -> d_out (128 floats)
//
// Workspace budget: 2*51.2MB feature bufs + ~5MB CSR/scan = ~107.5MB.

#define NEG_SLOPE 0.2f

__device__ __forceinline__ float leaky(float x) { return x > 0.0f ? x : NEG_SLOPE * x; }

// ---------------- CSR build ----------------
__global__ void hist_kernel(const int* __restrict__ dst, int* __restrict__ deg, int E) {
  int e = blockIdx.x * 256 + threadIdx.x;
  if (e < E) atomicAdd(&deg[dst[e]], 1);
}

// per-1024-chunk exclusive scan + chunk totals
__global__ void scan_a(const int* __restrict__ cnt, int* __restrict__ exc,
                       int* __restrict__ bsum, int n) {
  __shared__ int sh[256];
  int b = blockIdx.x, tid = threadIdx.x;
  int base = b * 1024 + tid * 4;
  int v[4];
#pragma unroll
  for (int i = 0; i < 4; i++) v[i] = (base + i < n) ? cnt[base + i] : 0;
  int tsum = v[0] + v[1] + v[2] + v[3];
  sh[tid] = tsum;
  __syncthreads();
  for (int o = 1; o < 256; o <<= 1) {
    int t = (tid >= o) ? sh[tid - o] : 0;
    __syncthreads();
    sh[tid] += t;
    __syncthreads();
  }
  if (tid == 255) bsum[b] = sh[255];
  int run = sh[tid] - tsum;  // exclusive prefix of this thread within chunk
#pragma unroll
  for (int i = 0; i < 4; i++) {
    if (base + i < n) exc[base + i] = run;
    run += v[i];
  }
}

// exclusive scan of chunk totals (nb <= 128)
__global__ void scan_b(const int* __restrict__ bsum, int* __restrict__ boff, int nb) {
  __shared__ int sh[128];
  int tid = threadIdx.x;
  int orig = (tid < nb) ? bsum[tid] : 0;
  sh[tid] = orig;
  __syncthreads();
  for (int o = 1; o < 128; o <<= 1) {
    int t = (tid >= o) ? sh[tid - o] : 0;
    __syncthreads();
    sh[tid] += t;
    __syncthreads();
  }
  if (tid < nb) boff[tid] = sh[tid] - orig;
}

__global__ void scan_c(const int* __restrict__ exc, const int* __restrict__ boff,
                       int* __restrict__ rowst, int* __restrict__ fill, int n, int E) {
  int b = blockIdx.x, tid = threadIdx.x;
  int off = boff[b];
  int base = b * 1024 + tid * 4;
#pragma unroll
  for (int i = 0; i < 4; i++) {
    int idx = base + i;
    if (idx < n) {
      int v = exc[idx] + off;
      rowst[idx] = v;
      fill[idx] = v;
    }
  }
  if (b == 0 && tid == 0) rowst[n] = E;
}

__global__ void scatter_kernel(const int* __restrict__ src, const int* __restrict__ dst,
                               int* __restrict__ fill, int* __restrict__ esrc, int E) {
  int e = blockIdx.x * 256 + threadIdx.x;
  if (e < E) {
    int v = dst[e];
    int p = atomicAdd(&fill[v], 1);
    esrc[p] = src[e];
  }
}

// ---------------- GEMM: H[n,128] = X[n,128] @ W[128,128] (fp32 vector ALU) ----------
// block = 256 threads; tile = 64 rows x 128 cols; K tiled by 32.
__global__ __launch_bounds__(256) void gemm128(const float* __restrict__ X,
                                               const float* __restrict__ W,
                                               float* __restrict__ H, int n) {
  const int tid = threadIdx.x;
  const int tx = tid & 31;  // col group -> cols tx*4 .. tx*4+3
  const int ty = tid >> 5;  // row group -> rows ty*8 .. ty*8+7
  const int r0 = blockIdx.x * 64;
  __shared__ float Xs[64][33];   // [row][k], +1 pad
  __shared__ float Ws[32][132];  // [k][col], +4 pad (keeps float4 alignment)
  float acc[8][4];
#pragma unroll
  for (int r = 0; r < 8; r++)
#pragma unroll
    for (int c = 0; c < 4; c++) acc[r][c] = 0.f;

  const int lrow = tid >> 2;       // 0..63
  const int lkg = (tid & 3) * 8;   // 0,8,16,24

  for (int kt = 0; kt < 128; kt += 32) {
    // stage X tile
    {
      int grow = r0 + lrow;
      float4 v0, v1;
      if (grow < n) {
        v0 = *(const float4*)&X[(size_t)grow * 128 + kt + lkg];
        v1 = *(const float4*)&X[(size_t)grow * 128 + kt + lkg + 4];
      } else {
        v0 = make_float4(0.f, 0.f, 0.f, 0.f);
        v1 = v0;
      }
      Xs[lrow][lkg + 0] = v0.x; Xs[lrow][lkg + 1] = v0.y;
      Xs[lrow][lkg + 2] = v0.z; Xs[lrow][lkg + 3] = v0.w;
      Xs[lrow][lkg + 4] = v1.x; Xs[lrow][lkg + 5] = v1.y;
      Xs[lrow][lkg + 6] = v1.z; Xs[lrow][lkg + 7] = v1.w;
    }
    // stage W tile (32 k-rows x 128 cols)
#pragma unroll
    for (int j = 0; j < 4; j++) {
      int idx = tid + 256 * j;      // 0..1023 float4s
      int k = idx >> 5;
      int cg = (idx & 31) << 2;
      *(float4*)&Ws[k][cg] = *(const float4*)&W[(size_t)(kt + k) * 128 + cg];
    }
    __syncthreads();
#pragma unroll
    for (int k = 0; k < 32; k++) {
      float4 wv = *(const float4*)&Ws[k][tx * 4];
      float xr[8];
#pragma unroll
      for (int r = 0; r < 8; r++) xr[r] = Xs[ty * 8 + r][k];
#pragma unroll
      for (int r = 0; r < 8; r++) {
        acc[r][0] += xr[r] * wv.x;
        acc[r][1] += xr[r] * wv.y;
        acc[r][2] += xr[r] * wv.z;
        acc[r][3] += xr[r] * wv.w;
      }
    }
    __syncthreads();
  }
#pragma unroll
  for (int r = 0; r < 8; r++) {
    int grow = r0 + ty * 8 + r;
    if (grow < n) {
      float4 o = make_float4(acc[r][0], acc[r][1], acc[r][2], acc[r][3]);
      *(float4*)&H[(size_t)grow * 128 + tx * 4] = o;
    }
  }
}

// ---------------- per-node attention dots: as[v]=h[v].a_src, ad[v]=h[v].a_dst ------
__global__ __launch_bounds__(256) void dots_k(const float* __restrict__ H,
                                              const float* __restrict__ a_s,
                                              const float* __restrict__ a_d,
                                              float* __restrict__ vas,
                                              float* __restrict__ vad, int n) {
  int w = (blockIdx.x * 256 + threadIdx.x) >> 6;
  int lane = threadIdx.x & 63;
  if (w >= n) return;
  float h0 = H[(size_t)w * 128 + lane];
  float h1 = H[(size_t)w * 128 + 64 + lane];
  float s = h0 * a_s[lane] + h1 * a_s[64 + lane];
  float d = h0 * a_d[lane] + h1 * a_d[64 + lane];
#pragma unroll
  for (int o = 32; o; o >>= 1) {
    s += __shfl_xor(s, o, 64);
    d += __shfl_xor(d, o, 64);
  }
  if (lane == 0) {
    vas[w] = s;
    vad[w] = d;
  }
}

// ---------------- GAT aggregation: one wave per dst node ----------------
__global__ __launch_bounds__(256) void gat_agg(const float* __restrict__ H,
                                               const float* __restrict__ vas,
                                               const float* __restrict__ vad,
                                               const int* __restrict__ rowst,
                                               const int* __restrict__ esrc,
                                               const float* __restrict__ bias,
                                               float* __restrict__ Out, int n,
                                               int do_relu) {
  int w = (blockIdx.x * 256 + threadIdx.x) >> 6;
  int lane = threadIdx.x & 63;
  if (w >= n) return;
  int s = rowst[w], e = rowst[w + 1];
  float adv = vad[w];
  float eself = leaky(vas[w] + adv);
  // pass 1: segment max (incl. self loop)
  float m = eself;
  for (int j = s + lane; j < e; j += 64) {
    m = fmaxf(m, leaky(vas[esrc[j]] + adv));
  }
#pragma unroll
  for (int o = 32; o; o >>= 1) m = fmaxf(m, __shfl_xor(m, o, 64));
  // pass 2: unnormalized weighted sum + denominator
  const float2* __restrict__ H2 = (const float2*)H;
  float wself = expf(eself - m);
  float2 hv = H2[(size_t)w * 64 + lane];
  float2 acc;
  acc.x = wself * hv.x;
  acc.y = wself * hv.y;
  float dsum = 0.f;
  for (int base = s; base < e; base += 64) {
    int j = base + lane;
    float wj = 0.f;
    int uj = 0;
    if (j < e) {
      uj = esrc[j];
      wj = expf(leaky(vas[uj] + adv) - m);
    }
    dsum += wj;
    int cnt = min(64, e - base);
    for (int t = 0; t < cnt; t++) {
      float wt = __shfl(wj, t, 64);
      int ut = __shfl(uj, t, 64);
      float2 hu = H2[(size_t)ut * 64 + lane];
      acc.x += wt * hu.x;
      acc.y += wt * hu.y;
    }
  }
#pragma unroll
  for (int o = 32; o; o >>= 1) dsum += __shfl_xor(dsum, o, 64);
  float inv = 1.0f / (dsum + wself);
  acc.x = acc.x * inv + bias[lane * 2];
  acc.y = acc.y * inv + bias[lane * 2 + 1];
  if (do_relu) {
    acc.x = fmaxf(acc.x, 0.f);
    acc.y = fmaxf(acc.y, 0.f);
  }
  ((float2*)Out)[(size_t)w * 64 + lane] = acc;
}

// ---------------- mean over nodes ----------------
__global__ __launch_bounds__(256) void mean_k(const float* __restrict__ O,
                                              float* __restrict__ out, int n,
                                              float invn) {
  int col = threadIdx.x & 127;
  int half = threadIdx.x >> 7;  // 0/1
  int r0 = blockIdx.x * 256;
  float acc = 0.f;
  int rend = min(r0 + 256, n);
  for (int r = r0 + half; r < rend; r += 2) acc += O[(size_t)r * 128 + col];
  __shared__ float sh[256];
  sh[threadIdx.x] = acc;
  __syncthreads();
  if (half == 0) atomicAdd(&out[col], (sh[threadIdx.x] + sh[threadIdx.x + 128]) * invn);
}

extern "C" void kernel_launch(void* const* d_in, const int* in_sizes, int n_in,
                              void* d_out, int out_size, void* d_ws, size_t ws_size,
                              hipStream_t stream) {
  const float* x = (const float*)d_in[0];
  const int* ei = (const int*)d_in[1];
  const float* W1 = (const float*)d_in[2];
  const float* a_src1 = (const float*)d_in[3];
  const float* a_dst1 = (const float*)d_in[4];
  const float* b1 = (const float*)d_in[5];
  const float* W2 = (const float*)d_in[6];
  const float* a_src2 = (const float*)d_in[7];
  const float* a_dst2 = (const float*)d_in[8];
  const float* b2 = (const float*)d_in[9];
  float* out = (float*)d_out;

  const int N = in_sizes[0] / 128;
  const int E = in_sizes[1] / 2;
  const int* src = ei;
  const int* dst = ei + E;

  char* p = (char*)d_ws;
  float* bufA = (float*)p; p += (size_t)N * 128 * 4;
  float* bufB = (float*)p; p += (size_t)N * 128 * 4;
  float* vas = (float*)p;  p += (size_t)N * 4;
  float* vad = (float*)p;  p += (size_t)N * 4;
  int* deg = (int*)p;      p += (size_t)N * 4;
  int* rowst = (int*)p;    p += (size_t)(N + 1) * 4;
  int* fill = (int*)p;     p += (size_t)N * 4;
  int* esrc = (int*)p;     p += (size_t)E * 4;
  int* exc = (int*)p;      p += (size_t)N * 4;
  int* bsum = (int*)p;     p += 128 * 4;
  int* boff = (int*)p;     p += 128 * 4;

  const int nb = (N + 1023) / 1024;         // 98 for N=100000 (<=128 required)
  const int eblocks = (E + 255) / 256;
  const int nwblocks = (N * 64 + 255) / 256;  // one wave per node

  // --- CSR over dst (rebuilt every call; ws is poisoned between calls) ---
  hipMemsetAsync(deg, 0, (size_t)N * 4, stream);
  hist_kernel<<<eblocks, 256, 0, stream>>>(dst, deg, E);
  scan_a<<<nb, 256, 0, stream>>>(deg, exc, bsum, N);
  scan_b<<<1, 128, 0, stream>>>(bsum, boff, nb);
  scan_c<<<nb, 256, 0, stream>>>(exc, boff, rowst, fill, N, E);
  scatter_kernel<<<eblocks, 256, 0, stream>>>(src, dst, fill, esrc, E);

  // --- layer 1 ---
  gemm128<<<(N + 63) / 64, 256, 0, stream>>>(x, W1, bufA, N);
  dots_k<<<nwblocks, 256, 0, stream>>>(bufA, a_src1, a_dst1, vas, vad, N);
  gat_agg<<<nwblocks, 256, 0, stream>>>(bufA, vas, vad, rowst, esrc, b1, bufB, N, 1);

  // --- layer 2 ---
  gemm128<<<(N + 63) / 64, 256, 0, stream>>>(bufB, W2, bufA, N);
  dots_k<<<nwblocks, 256, 0, stream>>>(bufA, a_src2, a_dst2, vas, vad, N);
  gat_agg<<<nwblocks, 256, 0, stream>>>(bufA, vas, vad, rowst, esrc, b2, bufB, N, 0);

  // --- mean ---
  hipMemsetAsync(out, 0, 128 * 4, stream);
  mean_k<<<(N + 255) / 256, 256, 0, stream>>>(bufB, out, N, 1.0f / (float)N);
}

// Round 2
// 433.780 us; speedup vs baseline: 1.0985x; 1.0985x over previous
//
#include <hip/hip_runtime.h>

// PersonaGNN: 2-layer GAT, N=100000 nodes, E=600000 edges (+ self loops),
// all dims 128, fp32 in/out, edge_index int32 [2][E].
//
// R2 changes vs R1:
//  - gat_agg: deg<=64 fast path gathers vas once per edge; feature-gather
//    broadcast loop batched 8-deep (8 outstanding loads) to kill the
//    serial bpermute->load->waitcnt chain; node id forced to SGPR.
//  - dots_k fused into gemm128 epilogue (deletes 2 dispatches, 2x51MB reads).

#define NEG_SLOPE 0.2f

__device__ __forceinline__ float leaky(float x) { return x > 0.0f ? x : NEG_SLOPE * x; }

// ---------------- CSR build ----------------
__global__ void hist_kernel(const int* __restrict__ dst, int* __restrict__ deg, int E) {
  int e = blockIdx.x * 256 + threadIdx.x;
  if (e < E) atomicAdd(&deg[dst[e]], 1);
}

// per-1024-chunk exclusive scan + chunk totals
__global__ void scan_a(const int* __restrict__ cnt, int* __restrict__ exc,
                       int* __restrict__ bsum, int n) {
  __shared__ int sh[256];
  int b = blockIdx.x, tid = threadIdx.x;
  int base = b * 1024 + tid * 4;
  int v[4];
#pragma unroll
  for (int i = 0; i < 4; i++) v[i] = (base + i < n) ? cnt[base + i] : 0;
  int tsum = v[0] + v[1] + v[2] + v[3];
  sh[tid] = tsum;
  __syncthreads();
  for (int o = 1; o < 256; o <<= 1) {
    int t = (tid >= o) ? sh[tid - o] : 0;
    __syncthreads();
    sh[tid] += t;
    __syncthreads();
  }
  if (tid == 255) bsum[b] = sh[255];
  int run = sh[tid] - tsum;
#pragma unroll
  for (int i = 0; i < 4; i++) {
    if (base + i < n) exc[base + i] = run;
    run += v[i];
  }
}

__global__ void scan_b(const int* __restrict__ bsum, int* __restrict__ boff, int nb) {
  __shared__ int sh[128];
  int tid = threadIdx.x;
  int orig = (tid < nb) ? bsum[tid] : 0;
  sh[tid] = orig;
  __syncthreads();
  for (int o = 1; o < 128; o <<= 1) {
    int t = (tid >= o) ? sh[tid - o] : 0;
    __syncthreads();
    sh[tid] += t;
    __syncthreads();
  }
  if (tid < nb) boff[tid] = sh[tid] - orig;
}

__global__ void scan_c(const int* __restrict__ exc, const int* __restrict__ boff,
                       int* __restrict__ rowst, int* __restrict__ fill, int n, int E) {
  int b = blockIdx.x, tid = threadIdx.x;
  int off = boff[b];
  int base = b * 1024 + tid * 4;
#pragma unroll
  for (int i = 0; i < 4; i++) {
    int idx = base + i;
    if (idx < n) {
      int v = exc[idx] + off;
      rowst[idx] = v;
      fill[idx] = v;
    }
  }
  if (b == 0 && tid == 0) rowst[n] = E;
}

__global__ void scatter_kernel(const int* __restrict__ src, const int* __restrict__ dst,
                               int* __restrict__ fill, int* __restrict__ esrc, int E) {
  int e = blockIdx.x * 256 + threadIdx.x;
  if (e < E) {
    int v = dst[e];
    int p = atomicAdd(&fill[v], 1);
    esrc[p] = src[e];
  }
}

// ------- GEMM: H[n,128] = X[n,128] @ W[128,128] + fused attention dots -------
// block = 256 threads; tile = 64 rows x 128 cols; K tiled by 32.
// Epilogue also computes vas[r]=h[r].a_src, vad[r]=h[r].a_dst per row.
__global__ __launch_bounds__(256) void gemm128(const float* __restrict__ X,
                                               const float* __restrict__ W,
                                               const float* __restrict__ a_s,
                                               const float* __restrict__ a_d,
                                               float* __restrict__ H,
                                               float* __restrict__ vas,
                                               float* __restrict__ vad, int n) {
  const int tid = threadIdx.x;
  const int tx = tid & 31;  // col group -> cols tx*4 .. tx*4+3
  const int ty = tid >> 5;  // row group -> rows ty*8 .. ty*8+7
  const int r0 = blockIdx.x * 64;
  __shared__ float Xs[64][33];   // [row][k], +1 pad
  __shared__ float Ws[32][132];  // [k][col], +4 pad
  float acc[8][4];
#pragma unroll
  for (int r = 0; r < 8; r++)
#pragma unroll
    for (int c = 0; c < 4; c++) acc[r][c] = 0.f;

  const int lrow = tid >> 2;
  const int lkg = (tid & 3) * 8;

  const float4 as4 = *(const float4*)&a_s[tx * 4];
  const float4 ad4 = *(const float4*)&a_d[tx * 4];

  for (int kt = 0; kt < 128; kt += 32) {
    {
      int grow = r0 + lrow;
      float4 v0, v1;
      if (grow < n) {
        v0 = *(const float4*)&X[(size_t)grow * 128 + kt + lkg];
        v1 = *(const float4*)&X[(size_t)grow * 128 + kt + lkg + 4];
      } else {
        v0 = make_float4(0.f, 0.f, 0.f, 0.f);
        v1 = v0;
      }
      Xs[lrow][lkg + 0] = v0.x; Xs[lrow][lkg + 1] = v0.y;
      Xs[lrow][lkg + 2] = v0.z; Xs[lrow][lkg + 3] = v0.w;
      Xs[lrow][lkg + 4] = v1.x; Xs[lrow][lkg + 5] = v1.y;
      Xs[lrow][lkg + 6] = v1.z; Xs[lrow][lkg + 7] = v1.w;
    }
#pragma unroll
    for (int j = 0; j < 4; j++) {
      int idx = tid + 256 * j;
      int k = idx >> 5;
      int cg = (idx & 31) << 2;
      *(float4*)&Ws[k][cg] = *(const float4*)&W[(size_t)(kt + k) * 128 + cg];
    }
    __syncthreads();
#pragma unroll
    for (int k = 0; k < 32; k++) {
      float4 wv = *(const float4*)&Ws[k][tx * 4];
      float xr[8];
#pragma unroll
      for (int r = 0; r < 8; r++) xr[r] = Xs[ty * 8 + r][k];
#pragma unroll
      for (int r = 0; r < 8; r++) {
        acc[r][0] += xr[r] * wv.x;
        acc[r][1] += xr[r] * wv.y;
        acc[r][2] += xr[r] * wv.z;
        acc[r][3] += xr[r] * wv.w;
      }
    }
    __syncthreads();
  }
#pragma unroll
  for (int r = 0; r < 8; r++) {
    int grow = r0 + ty * 8 + r;
    if (grow < n) {
      float4 o = make_float4(acc[r][0], acc[r][1], acc[r][2], acc[r][3]);
      *(float4*)&H[(size_t)grow * 128 + tx * 4] = o;
    }
    // fused dots: reduce h[grow] . a_src / a_dst across the 32 tx lanes
    float ds_ = acc[r][0] * as4.x + acc[r][1] * as4.y + acc[r][2] * as4.z + acc[r][3] * as4.w;
    float dd_ = acc[r][0] * ad4.x + acc[r][1] * ad4.y + acc[r][2] * ad4.z + acc[r][3] * ad4.w;
#pragma unroll
    for (int o = 16; o; o >>= 1) {
      ds_ += __shfl_xor(ds_, o, 64);
      dd_ += __shfl_xor(dd_, o, 64);
    }
    if (tx == 0 && grow < n) {
      vas[grow] = ds_;
      vad[grow] = dd_;
    }
  }
}

// ---------------- GAT aggregation: one wave per dst node ----------------
__global__ __launch_bounds__(256) void gat_agg(const float* __restrict__ H,
                                               const float* __restrict__ vas,
                                               const float* __restrict__ vad,
                                               const int* __restrict__ rowst,
                                               const int* __restrict__ esrc,
                                               const float* __restrict__ bias,
                                               float* __restrict__ Out, int n,
                                               int do_relu) {
  int w = (blockIdx.x * 256 + threadIdx.x) >> 6;
  int lane = threadIdx.x & 63;
  if (w >= n) return;
  w = __builtin_amdgcn_readfirstlane(w);  // force scalar addressing for row bounds
  const int s = rowst[w];
  const int e = rowst[w + 1];
  const int deg = e - s;
  const float adv = vad[w];
  const float eself = leaky(vas[w] + adv);
  const float2* __restrict__ H2 = (const float2*)H;

  float2 hv = H2[(size_t)w * 64 + lane];
  float2 acc;
  float dsum = 0.f;
  float wself;

  if (deg <= 64) {
    // ---- fast path: one gather of vas per edge, then batched feature gathers
    int uj = 0;
    float ej = -1e30f;
    const bool act = lane < deg;
    if (act) {
      uj = esrc[s + lane];
      ej = leaky(vas[uj] + adv);
    }
    float m = fmaxf(eself, ej);
#pragma unroll
    for (int o = 32; o; o >>= 1) m = fmaxf(m, __shfl_xor(m, o, 64));
    float wj = act ? __expf(ej - m) : 0.f;
    dsum = wj;
    wself = __expf(eself - m);
    acc.x = wself * hv.x;
    acc.y = wself * hv.y;
#pragma unroll 1
    for (int t0 = 0; t0 < deg; t0 += 8) {
      const int tb = deg - t0;  // wave-uniform
      float2 hb[8];
      float wt[8];
#pragma unroll
      for (int i = 0; i < 8; i++) {
        if (i < tb) {
          int ut = __shfl(uj, t0 + i, 64);
          wt[i] = __shfl(wj, t0 + i, 64);
          hb[i] = H2[(size_t)ut * 64 + lane];
        }
      }
#pragma unroll
      for (int i = 0; i < 8; i++) {
        if (i < tb) {
          acc.x += wt[i] * hb[i].x;
          acc.y += wt[i] * hb[i].y;
        }
      }
    }
  } else {
    // ---- generic path (rare): two passes, still batched
    float m = eself;
    for (int j = s + lane; j < e; j += 64) m = fmaxf(m, leaky(vas[esrc[j]] + adv));
#pragma unroll
    for (int o = 32; o; o >>= 1) m = fmaxf(m, __shfl_xor(m, o, 64));
    wself = __expf(eself - m);
    acc.x = wself * hv.x;
    acc.y = wself * hv.y;
    for (int base = s; base < e; base += 64) {
      int j = base + lane;
      float wj = 0.f;
      int uj = 0;
      if (j < e) {
        uj = esrc[j];
        wj = __expf(leaky(vas[uj] + adv) - m);
      }
      dsum += wj;
      const int cnt = min(64, e - base);
      for (int t0 = 0; t0 < cnt; t0 += 8) {
        const int tb = cnt - t0;
        float2 hb[8];
        float wt[8];
#pragma unroll
        for (int i = 0; i < 8; i++) {
          if (i < tb) {
            int ut = __shfl(uj, t0 + i, 64);
            wt[i] = __shfl(wj, t0 + i, 64);
            hb[i] = H2[(size_t)ut * 64 + lane];
          }
        }
#pragma unroll
        for (int i = 0; i < 8; i++) {
          if (i < tb) {
            acc.x += wt[i] * hb[i].x;
            acc.y += wt[i] * hb[i].y;
          }
        }
      }
    }
  }
#pragma unroll
  for (int o = 32; o; o >>= 1) dsum += __shfl_xor(dsum, o, 64);
  float inv = 1.0f / (dsum + wself);
  acc.x = acc.x * inv + bias[lane * 2];
  acc.y = acc.y * inv + bias[lane * 2 + 1];
  if (do_relu) {
    acc.x = fmaxf(acc.x, 0.f);
    acc.y = fmaxf(acc.y, 0.f);
  }
  ((float2*)Out)[(size_t)w * 64 + lane] = acc;
}

// ---------------- mean over nodes ----------------
__global__ __launch_bounds__(256) void mean_k(const float* __restrict__ O,
                                              float* __restrict__ out, int n,
                                              float invn) {
  int col = threadIdx.x & 127;
  int half = threadIdx.x >> 7;
  int r0 = blockIdx.x * 256;
  float acc = 0.f;
  int rend = min(r0 + 256, n);
  for (int r = r0 + half; r < rend; r += 2) acc += O[(size_t)r * 128 + col];
  __shared__ float sh[256];
  sh[threadIdx.x] = acc;
  __syncthreads();
  if (half == 0) atomicAdd(&out[col], (sh[threadIdx.x] + sh[threadIdx.x + 128]) * invn);
}

extern "C" void kernel_launch(void* const* d_in, const int* in_sizes, int n_in,
                              void* d_out, int out_size, void* d_ws, size_t ws_size,
                              hipStream_t stream) {
  const float* x = (const float*)d_in[0];
  const int* ei = (const int*)d_in[1];
  const float* W1 = (const float*)d_in[2];
  const float* a_src1 = (const float*)d_in[3];
  const float* a_dst1 = (const float*)d_in[4];
  const float* b1 = (const float*)d_in[5];
  const float* W2 = (const float*)d_in[6];
  const float* a_src2 = (const float*)d_in[7];
  const float* a_dst2 = (const float*)d_in[8];
  const float* b2 = (const float*)d_in[9];
  float* out = (float*)d_out;

  const int N = in_sizes[0] / 128;
  const int E = in_sizes[1] / 2;
  const int* src = ei;
  const int* dst = ei + E;

  char* p = (char*)d_ws;
  float* bufA = (float*)p; p += (size_t)N * 128 * 4;
  float* bufB = (float*)p; p += (size_t)N * 128 * 4;
  float* vas = (float*)p;  p += (size_t)N * 4;
  float* vad = (float*)p;  p += (size_t)N * 4;
  int* deg = (int*)p;      p += (size_t)N * 4;
  int* rowst = (int*)p;    p += (size_t)(N + 1) * 4;
  int* fill = (int*)p;     p += (size_t)N * 4;
  int* esrc = (int*)p;     p += (size_t)E * 4;
  int* exc = (int*)p;      p += (size_t)N * 4;
  int* bsum = (int*)p;     p += 128 * 4;
  int* boff = (int*)p;     p += 128 * 4;

  const int nb = (N + 1023) / 1024;  // 98 for N=100000 (<=128 required)
  const int eblocks = (E + 255) / 256;
  const int nwblocks = (N * 64 + 255) / 256;  // one wave per node

  // --- CSR over dst ---
  hipMemsetAsync(deg, 0, (size_t)N * 4, stream);
  hist_kernel<<<eblocks, 256, 0, stream>>>(dst, deg, E);
  scan_a<<<nb, 256, 0, stream>>>(deg, exc, bsum, N);
  scan_b<<<1, 128, 0, stream>>>(bsum, boff, nb);
  scan_c<<<nb, 256, 0, stream>>>(exc, boff, rowst, fill, N, E);
  scatter_kernel<<<eblocks, 256, 0, stream>>>(src, dst, fill, esrc, E);

  // --- layer 1 ---
  gemm128<<<(N + 63) / 64, 256, 0, stream>>>(x, W1, a_src1, a_dst1, bufA, vas, vad, N);
  gat_agg<<<nwblocks, 256, 0, stream>>>(bufA, vas, vad, rowst, esrc, b1, bufB, N, 1);

  // --- layer 2 ---
  gemm128<<<(N + 63) / 64, 256, 0, stream>>>(bufB, W2, a_src2, a_dst2, bufA, vas, vad, N);
  gat_agg<<<nwblocks, 256, 0, stream>>>(bufA, vas, vad, rowst, esrc, b2, bufB, N, 0);

  // --- mean ---
  hipMemsetAsync(out, 0, 128 * 4, stream);
  mean_k<<<(N + 255) / 256, 256, 0, stream>>>(bufB, out, N, 1.0f / (float)N);
}

// Round 3
// 364.142 us; speedup vs baseline: 1.3085x; 1.1912x over previous
//
#include <hip/hip_runtime.h>

// PersonaGNN: 2-layer GAT, N=100000, E=600000 (+self loops), dims 128, fp32 io.
//
// R3: bf16+MFMA pipeline.
//  - cast x -> bf16 once; W cast+transposed into XOR-swizzled LDS per block.
//  - gemm_mfma: v_mfma_f32_16x16x32_bf16, A-frags straight from global
//    (A[m=lane&15][k=quad*8+j]), B-frags via ds_read_b128 from swizzled Wt.
//    Fused vas/vad dots from fp32 accumulators. H stored bf16.
//  - gat_agg gathers bf16 rows (256B/row, L3-resident), fp32 accumulate;
//    layer1 writes packed bf16 (direct GEMM-2 input), layer2 writes fp32.
//  - CSR build unchanged (R4 target).

#define NEG_SLOPE 0.2f

typedef __attribute__((ext_vector_type(8))) short bf16x8;
typedef __attribute__((ext_vector_type(4))) float f32x4;

__device__ __forceinline__ float leaky(float x) { return x > 0.0f ? x : NEG_SLOPE * x; }

__device__ __forceinline__ unsigned int bf16rne(float f) {
  unsigned int u = __float_as_uint(f);
  return (u + 0x7fffu + ((u >> 16) & 1u)) >> 16;
}
__device__ __forceinline__ unsigned int packbf(float a, float b) {
  return bf16rne(a) | (bf16rne(b) << 16);
}
__device__ __forceinline__ float bf_lo(unsigned int u) { return __uint_as_float(u << 16); }
__device__ __forceinline__ float bf_hi(unsigned int u) { return __uint_as_float(u & 0xffff0000u); }

// ---------------- CSR build ----------------
__global__ void hist_kernel(const int* __restrict__ dst, int* __restrict__ deg, int E) {
  int e = blockIdx.x * 256 + threadIdx.x;
  if (e < E) atomicAdd(&deg[dst[e]], 1);
}

__global__ void scan_a(const int* __restrict__ cnt, int* __restrict__ exc,
                       int* __restrict__ bsum, int n) {
  __shared__ int sh[256];
  int b = blockIdx.x, tid = threadIdx.x;
  int base = b * 1024 + tid * 4;
  int v[4];
#pragma unroll
  for (int i = 0; i < 4; i++) v[i] = (base + i < n) ? cnt[base + i] : 0;
  int tsum = v[0] + v[1] + v[2] + v[3];
  sh[tid] = tsum;
  __syncthreads();
  for (int o = 1; o < 256; o <<= 1) {
    int t = (tid >= o) ? sh[tid - o] : 0;
    __syncthreads();
    sh[tid] += t;
    __syncthreads();
  }
  if (tid == 255) bsum[b] = sh[255];
  int run = sh[tid] - tsum;
#pragma unroll
  for (int i = 0; i < 4; i++) {
    if (base + i < n) exc[base + i] = run;
    run += v[i];
  }
}

__global__ void scan_b(const int* __restrict__ bsum, int* __restrict__ boff, int nb) {
  __shared__ int sh[128];
  int tid = threadIdx.x;
  int orig = (tid < nb) ? bsum[tid] : 0;
  sh[tid] = orig;
  __syncthreads();
  for (int o = 1; o < 128; o <<= 1) {
    int t = (tid >= o) ? sh[tid - o] : 0;
    __syncthreads();
    sh[tid] += t;
    __syncthreads();
  }
  if (tid < nb) boff[tid] = sh[tid] - orig;
}

__global__ void scan_c(const int* __restrict__ exc, const int* __restrict__ boff,
                       int* __restrict__ rowst, int* __restrict__ fill, int n, int E) {
  int b = blockIdx.x, tid = threadIdx.x;
  int off = boff[b];
  int base = b * 1024 + tid * 4;
#pragma unroll
  for (int i = 0; i < 4; i++) {
    int idx = base + i;
    if (idx < n) {
      int v = exc[idx] + off;
      rowst[idx] = v;
      fill[idx] = v;
    }
  }
  if (b == 0 && tid == 0) rowst[n] = E;
}

__global__ void scatter_kernel(const int* __restrict__ src, const int* __restrict__ dst,
                               int* __restrict__ fill, int* __restrict__ esrc, int E) {
  int e = blockIdx.x * 256 + threadIdx.x;
  if (e < E) {
    int v = dst[e];
    int p = atomicAdd(&fill[v], 1);
    esrc[p] = src[e];
  }
}

// ---------------- fp32 -> bf16 cast (8 elements/thread) ----------------
__global__ __launch_bounds__(256) void cast_bf16_k(const float* __restrict__ X,
                                                   unsigned int* __restrict__ Xh,
                                                   long total8) {
  long i = (long)blockIdx.x * 256 + threadIdx.x;
  if (i >= total8) return;
  const float4* X4 = (const float4*)X;
  float4 a = X4[i * 2], b = X4[i * 2 + 1];
  uint4 o;
  o.x = packbf(a.x, a.y);
  o.y = packbf(a.z, a.w);
  o.z = packbf(b.x, b.y);
  o.w = packbf(b.z, b.w);
  ((uint4*)Xh)[i] = o;
}

// ------- MFMA GEMM: H[n,128](bf16) = Xh[n,128](bf16) @ W(f32->bf16), + dots -----
// block = 256 (4 waves); each wave does 16 rows x 128 cols; K=128 in 4 steps.
__global__ __launch_bounds__(256) void gemm_mfma(const unsigned short* __restrict__ Xh,
                                                 const float* __restrict__ W,
                                                 const float* __restrict__ a_s,
                                                 const float* __restrict__ a_d,
                                                 unsigned short* __restrict__ H,
                                                 float* __restrict__ vas,
                                                 float* __restrict__ vad, int n) {
  __shared__ unsigned short Wt[128 * 128];  // Wt[n][k] bf16, 16B chunks XOR-swizzled by (n&7)
  const int tid = threadIdx.x;
  const int lane = tid & 63;
  const int wv = tid >> 6;
  const int l15 = lane & 15;
  const int q = lane >> 4;

  // stage W -> Wt (transpose + cast), 16 iters/thread
  for (int i = tid; i < 128 * 32; i += 256) {
    int k = i >> 5;            // 0..127
    int ng = (i & 31) << 2;    // n0: 0..124
    float4 w4 = *(const float4*)&W[(size_t)k * 128 + ng];
    float wa[4] = {w4.x, w4.y, w4.z, w4.w};
#pragma unroll
    for (int j = 0; j < 4; j++) {
      int nn = ng + j;
      Wt[nn * 128 + (((k >> 3) ^ (nn & 7)) << 3) + (k & 7)] = (unsigned short)bf16rne(wa[j]);
    }
  }
  __syncthreads();

  const int row0 = blockIdx.x * 64 + wv * 16;
  const int myrow = row0 + l15;  // A row this lane loads (padded buffer: safe)

  f32x4 acc[8];
#pragma unroll
  for (int ct = 0; ct < 8; ct++) acc[ct] = (f32x4){0.f, 0.f, 0.f, 0.f};

#pragma unroll
  for (int ks = 0; ks < 4; ks++) {
    bf16x8 afrag = *(const bf16x8*)&Xh[(size_t)myrow * 128 + ks * 32 + q * 8];
    const int kchunk = ks * 4 + q;
#pragma unroll
    for (int ct = 0; ct < 8; ct++) {
      const int nn = ct * 16 + l15;
      bf16x8 bfrag = *(const bf16x8*)&Wt[nn * 128 + (((kchunk) ^ (nn & 7)) << 3)];
      acc[ct] = __builtin_amdgcn_mfma_f32_16x16x32_bf16(afrag, bfrag, acc[ct], 0, 0, 0);
    }
  }

  // attention vectors for the dots
  float as8[8], ad8[8];
#pragma unroll
  for (int ct = 0; ct < 8; ct++) {
    as8[ct] = a_s[ct * 16 + l15];
    ad8[ct] = a_d[ct * 16 + l15];
  }

  // epilogue: C/D layout col=lane&15, row=q*4+reg
#pragma unroll
  for (int r = 0; r < 4; r++) {
    int grow = row0 + q * 4 + r;
    float ds = 0.f, dd = 0.f;
#pragma unroll
    for (int ct = 0; ct < 8; ct++) {
      ds += acc[ct][r] * as8[ct];
      dd += acc[ct][r] * ad8[ct];
    }
#pragma unroll
    for (int o = 8; o; o >>= 1) {
      ds += __shfl_xor(ds, o, 64);
      dd += __shfl_xor(dd, o, 64);
    }
    if (grow < n) {
      if (l15 == 0) {
        vas[grow] = ds;
        vad[grow] = dd;
      }
#pragma unroll
      for (int ct = 0; ct < 8; ct++) {
        H[(size_t)grow * 128 + ct * 16 + l15] = (unsigned short)bf16rne(acc[ct][r]);
      }
    }
  }
}

// ---------------- GAT aggregation: one wave per dst node, bf16 gathers ----------
__global__ __launch_bounds__(256) void gat_agg(const unsigned short* __restrict__ H,
                                               const float* __restrict__ vas,
                                               const float* __restrict__ vad,
                                               const int* __restrict__ rowst,
                                               const int* __restrict__ esrc,
                                               const float* __restrict__ bias,
                                               void* __restrict__ Out, int n,
                                               int relu_bf16out) {
  int w = (blockIdx.x * 256 + threadIdx.x) >> 6;
  int lane = threadIdx.x & 63;
  if (w >= n) return;
  w = __builtin_amdgcn_readfirstlane(w);
  const int s = rowst[w];
  const int e = rowst[w + 1];
  const int deg = e - s;
  const float adv = vad[w];
  const float eself = leaky(vas[w] + adv);
  const unsigned int* __restrict__ Hu = (const unsigned int*)H;  // word i = cols 2i,2i+1

  unsigned int selfu = Hu[(size_t)w * 64 + lane];
  float2 acc;
  float dsum = 0.f;
  float wself;

  if (deg <= 64) {
    int uj = 0;
    float ej = -1e30f;
    const bool act = lane < deg;
    if (act) {
      uj = esrc[s + lane];
      ej = leaky(vas[uj] + adv);
    }
    float m = fmaxf(eself, ej);
#pragma unroll
    for (int o = 32; o; o >>= 1) m = fmaxf(m, __shfl_xor(m, o, 64));
    float wj = act ? __expf(ej - m) : 0.f;
    dsum = wj;
    wself = __expf(eself - m);
    acc.x = wself * bf_lo(selfu);
    acc.y = wself * bf_hi(selfu);
#pragma unroll 1
    for (int t0 = 0; t0 < deg; t0 += 8) {
      const int tb = deg - t0;  // wave-uniform
      unsigned int hb[8];
      float wt[8];
#pragma unroll
      for (int i = 0; i < 8; i++) {
        if (i < tb) {
          int ut = __shfl(uj, t0 + i, 64);
          wt[i] = __shfl(wj, t0 + i, 64);
          hb[i] = Hu[(size_t)ut * 64 + lane];
        }
      }
#pragma unroll
      for (int i = 0; i < 8; i++) {
        if (i < tb) {
          acc.x += wt[i] * bf_lo(hb[i]);
          acc.y += wt[i] * bf_hi(hb[i]);
        }
      }
    }
  } else {
    float m = eself;
    for (int j = s + lane; j < e; j += 64) m = fmaxf(m, leaky(vas[esrc[j]] + adv));
#pragma unroll
    for (int o = 32; o; o >>= 1) m = fmaxf(m, __shfl_xor(m, o, 64));
    wself = __expf(eself - m);
    acc.x = wself * bf_lo(selfu);
    acc.y = wself * bf_hi(selfu);
    for (int base = s; base < e; base += 64) {
      int j = base + lane;
      float wj = 0.f;
      int uj = 0;
      if (j < e) {
        uj = esrc[j];
        wj = __expf(leaky(vas[uj] + adv) - m);
      }
      dsum += wj;
      const int cnt = min(64, e - base);
      for (int t0 = 0; t0 < cnt; t0 += 8) {
        const int tb = cnt - t0;
        unsigned int hb[8];
        float wt[8];
#pragma unroll
        for (int i = 0; i < 8; i++) {
          if (i < tb) {
            int ut = __shfl(uj, t0 + i, 64);
            wt[i] = __shfl(wj, t0 + i, 64);
            hb[i] = Hu[(size_t)ut * 64 + lane];
          }
        }
#pragma unroll
        for (int i = 0; i < 8; i++) {
          if (i < tb) {
            acc.x += wt[i] * bf_lo(hb[i]);
            acc.y += wt[i] * bf_hi(hb[i]);
          }
        }
      }
    }
  }
#pragma unroll
  for (int o = 32; o; o >>= 1) dsum += __shfl_xor(dsum, o, 64);
  float inv = 1.0f / (dsum + wself);
  acc.x = acc.x * inv + bias[lane * 2];
  acc.y = acc.y * inv + bias[lane * 2 + 1];
  if (relu_bf16out) {
    acc.x = fmaxf(acc.x, 0.f);
    acc.y = fmaxf(acc.y, 0.f);
    ((unsigned int*)Out)[(size_t)w * 64 + lane] = packbf(acc.x, acc.y);
  } else {
    ((float2*)Out)[(size_t)w * 64 + lane] = acc;
  }
}

// ---------------- mean over nodes ----------------
__global__ __launch_bounds__(256) void mean_k(const float* __restrict__ O,
                                              float* __restrict__ out, int n,
                                              float invn) {
  int col = threadIdx.x & 127;
  int half = threadIdx.x >> 7;
  int r0 = blockIdx.x * 256;
  float acc = 0.f;
  int rend = min(r0 + 256, n);
  for (int r = r0 + half; r < rend; r += 2) acc += O[(size_t)r * 128 + col];
  __shared__ float sh[256];
  sh[threadIdx.x] = acc;
  __syncthreads();
  if (half == 0) atomicAdd(&out[col], (sh[threadIdx.x] + sh[threadIdx.x + 128]) * invn);
}

extern "C" void kernel_launch(void* const* d_in, const int* in_sizes, int n_in,
                              void* d_out, int out_size, void* d_ws, size_t ws_size,
                              hipStream_t stream) {
  const float* x = (const float*)d_in[0];
  const int* ei = (const int*)d_in[1];
  const float* W1 = (const float*)d_in[2];
  const float* a_src1 = (const float*)d_in[3];
  const float* a_dst1 = (const float*)d_in[4];
  const float* b1 = (const float*)d_in[5];
  const float* W2 = (const float*)d_in[6];
  const float* a_src2 = (const float*)d_in[7];
  const float* a_dst2 = (const float*)d_in[8];
  const float* b2 = (const float*)d_in[9];
  float* out = (float*)d_out;

  const int N = in_sizes[0] / 128;
  const int E = in_sizes[1] / 2;
  const int* src = ei;
  const int* dst = ei + E;

  const size_t rowpadded = (size_t)(N + 64) * 128;  // bf16 feature buf elems (padded rows)

  char* p = (char*)d_ws;
  unsigned short* Xh = (unsigned short*)p; p += rowpadded * 2;   // layer-1 input (bf16)
  unsigned short* B1h = (unsigned short*)p; p += rowpadded * 2;  // layer-1 output (bf16)
  unsigned short* Hh = (unsigned short*)p; p += rowpadded * 2;   // per-layer GEMM output (bf16)
  float* Bf = (float*)Xh;  // final layer fp32 output aliases Xh+B1h (both dead by then)
  float* vas = (float*)p;  p += (size_t)N * 4;
  float* vad = (float*)p;  p += (size_t)N * 4;
  int* deg = (int*)p;      p += (size_t)N * 4;
  int* rowst = (int*)p;    p += (size_t)(N + 1) * 4;
  int* fill = (int*)p;     p += (size_t)N * 4;
  int* esrc = (int*)p;     p += (size_t)E * 4;
  int* exc = (int*)p;      p += (size_t)N * 4;
  int* bsum = (int*)p;     p += 128 * 4;
  int* boff = (int*)p;     p += 128 * 4;

  const int nb = (N + 1023) / 1024;  // <=128
  const int eblocks = (E + 255) / 256;
  const int nwblocks = (N * 64 + 255) / 256;  // one wave per node
  const long total8 = (long)N * 128 / 8;

  // --- CSR over dst ---
  hipMemsetAsync(deg, 0, (size_t)N * 4, stream);
  hist_kernel<<<eblocks, 256, 0, stream>>>(dst, deg, E);
  scan_a<<<nb, 256, 0, stream>>>(deg, exc, bsum, N);
  scan_b<<<1, 128, 0, stream>>>(bsum, boff, nb);
  scan_c<<<nb, 256, 0, stream>>>(exc, boff, rowst, fill, N, E);
  scatter_kernel<<<eblocks, 256, 0, stream>>>(src, dst, fill, esrc, E);

  // --- cast input to bf16 ---
  cast_bf16_k<<<(int)((total8 + 255) / 256), 256, 0, stream>>>(x, (unsigned int*)Xh, total8);

  // --- layer 1 ---
  gemm_mfma<<<(N + 63) / 64, 256, 0, stream>>>(Xh, W1, a_src1, a_dst1, Hh, vas, vad, N);
  gat_agg<<<nwblocks, 256, 0, stream>>>(Hh, vas, vad, rowst, esrc, b1, (void*)B1h, N, 1);

  // --- layer 2 ---
  gemm_mfma<<<(N + 63) / 64, 256, 0, stream>>>(B1h, W2, a_src2, a_dst2, Hh, vas, vad, N);
  gat_agg<<<nwblocks, 256, 0, stream>>>(Hh, vas, vad, rowst, esrc, b2, (void*)Bf, N, 0);

  // --- mean ---
  hipMemsetAsync(out, 0, 128 * 4, stream);
  mean_k<<<(N + 255) / 256, 256, 0, stream>>>(Bf, out, N, 1.0f / (float)N);
}

// Round 4
// 307.311 us; speedup vs baseline: 1.5505x; 1.1849x over previous
//
#include <hip/hip_runtime.h>

// PersonaGNN: 2-layer GAT, N=100000, E=600000 (+self loops), dims 128, fp32 io.
//
// R4:
//  - gat_agg2: 4 nodes per wave (16 lanes/node), uint4 (16B) feature gathers,
//    width-16 softmax reductions; layer-2 variant fuses the node-mean
//    (block LDS reduce -> 64-replica atomics -> finalize kernel), never
//    materializing the layer-2 node outputs.
//  - gemm_mfma: grid-stride (stage W once per block, loop row tiles),
//    swapped MFMA operands so each lane owns 4 consecutive H cols ->
//    packed dwordx2 stores + 2-level dot reduce; layer-1 reads fp32 x
//    directly (cast kernel deleted).
//  - scan_b fused into scan_c.

#define NEG_SLOPE 0.2f

typedef __attribute__((ext_vector_type(8))) short bf16x8;
typedef __attribute__((ext_vector_type(4))) float f32x4;

__device__ __forceinline__ float leaky(float x) { return x > 0.0f ? x : NEG_SLOPE * x; }

__device__ __forceinline__ unsigned int bf16rne(float f) {
  unsigned int u = __float_as_uint(f);
  return (u + 0x7fffu + ((u >> 16) & 1u)) >> 16;
}
__device__ __forceinline__ unsigned int packbf(float a, float b) {
  return bf16rne(a) | (bf16rne(b) << 16);
}
__device__ __forceinline__ float bf_lo(unsigned int u) { return __uint_as_float(u << 16); }
__device__ __forceinline__ float bf_hi(unsigned int u) { return __uint_as_float(u & 0xffff0000u); }

__device__ __forceinline__ void accum8(float* a, float w, uint4 h) {
  a[0] += w * bf_lo(h.x); a[1] += w * bf_hi(h.x);
  a[2] += w * bf_lo(h.y); a[3] += w * bf_hi(h.y);
  a[4] += w * bf_lo(h.z); a[5] += w * bf_hi(h.z);
  a[6] += w * bf_lo(h.w); a[7] += w * bf_hi(h.w);
}

// ---------------- CSR build ----------------
__global__ void hist_kernel(const int* __restrict__ dst, int* __restrict__ deg, int E) {
  int e = blockIdx.x * 256 + threadIdx.x;
  if (e < E) atomicAdd(&deg[dst[e]], 1);
}

__global__ void scan_a(const int* __restrict__ cnt, int* __restrict__ exc,
                       int* __restrict__ bsum, int n) {
  __shared__ int sh[256];
  int b = blockIdx.x, tid = threadIdx.x;
  int base = b * 1024 + tid * 4;
  int v[4];
#pragma unroll
  for (int i = 0; i < 4; i++) v[i] = (base + i < n) ? cnt[base + i] : 0;
  int tsum = v[0] + v[1] + v[2] + v[3];
  sh[tid] = tsum;
  __syncthreads();
  for (int o = 1; o < 256; o <<= 1) {
    int t = (tid >= o) ? sh[tid - o] : 0;
    __syncthreads();
    sh[tid] += t;
    __syncthreads();
  }
  if (tid == 255) bsum[b] = sh[255];
  int run = sh[tid] - tsum;
#pragma unroll
  for (int i = 0; i < 4; i++) {
    if (base + i < n) exc[base + i] = run;
    run += v[i];
  }
}

// fused: per-block offset = sum(bsum[0..bid)) computed in-block, then add.
__global__ void scan_c2(const int* __restrict__ exc, const int* __restrict__ bsum,
                        int* __restrict__ rowst, int* __restrict__ fill, int n, int E,
                        int nb) {
  __shared__ int red[256];
  int b = blockIdx.x, tid = threadIdx.x;
  red[tid] = (tid < b && tid < nb) ? bsum[tid] : 0;
  __syncthreads();
#pragma unroll
  for (int o = 128; o; o >>= 1) {
    if (tid < o) red[tid] += red[tid + o];
    __syncthreads();
  }
  int off = red[0];
  int base = b * 1024 + tid * 4;
#pragma unroll
  for (int i = 0; i < 4; i++) {
    int idx = base + i;
    if (idx < n) {
      int v = exc[idx] + off;
      rowst[idx] = v;
      fill[idx] = v;
    }
  }
  if (b == 0 && tid == 0) rowst[n] = E;
}

__global__ void scatter_kernel(const int* __restrict__ src, const int* __restrict__ dst,
                               int* __restrict__ fill, int* __restrict__ esrc, int E) {
  int e = blockIdx.x * 256 + threadIdx.x;
  if (e < E) {
    int v = dst[e];
    int p = atomicAdd(&fill[v], 1);
    esrc[p] = src[e];
  }
}

// ------- MFMA GEMM (grid-stride): H[n,128](bf16) = X[n,128] @ W, + dots -------
// block = 256 (4 waves); per tile-iter each wave does 16 X-rows x 128 cols.
// Operand-swapped: D[m=W-col][n=X-row] -> lane l15 = X-row, (q*4+r) = W-col
// within ct*16 block -> 4 consecutive cols per lane per ct.
template <bool F32IN>
__global__ __launch_bounds__(256) void gemm_mfma(const void* __restrict__ Xin,
                                                 const float* __restrict__ W,
                                                 const float* __restrict__ a_s,
                                                 const float* __restrict__ a_d,
                                                 unsigned short* __restrict__ H,
                                                 float* __restrict__ vas,
                                                 float* __restrict__ vad, int n,
                                                 int ntiles) {
  __shared__ unsigned short Wt[128 * 128];  // Wt[wcol][k] bf16, 16B-chunk XOR swizzle
  const int tid = threadIdx.x;
  const int lane = tid & 63;
  const int wv = tid >> 6;
  const int l15 = lane & 15;
  const int q = lane >> 4;

  // stage W -> Wt (transpose + cast) once per block
  for (int i = tid; i < 128 * 32; i += 256) {
    int k = i >> 5;
    int ng = (i & 31) << 2;
    float4 w4 = *(const float4*)&W[(size_t)k * 128 + ng];
    float wa[4] = {w4.x, w4.y, w4.z, w4.w};
#pragma unroll
    for (int j = 0; j < 4; j++) {
      int nn = ng + j;
      Wt[nn * 128 + (((k >> 3) ^ (nn & 7)) << 3) + (k & 7)] = (unsigned short)bf16rne(wa[j]);
    }
  }
  __syncthreads();

  const float* Xf = (const float*)Xin;
  const unsigned short* Xh = (const unsigned short*)Xin;

  for (int tile = blockIdx.x; tile < ntiles; tile += gridDim.x) {
    const int row0 = tile * 64 + wv * 16;
    const int myrow = row0 + l15;
    const bool act = myrow < n;

    f32x4 acc[8];
#pragma unroll
    for (int ct = 0; ct < 8; ct++) acc[ct] = (f32x4){0.f, 0.f, 0.f, 0.f};

#pragma unroll
    for (int ks = 0; ks < 4; ks++) {
      bf16x8 xfrag;
      if (F32IN) {
        float4 xa = {0, 0, 0, 0}, xb = {0, 0, 0, 0};
        if (act) {
          xa = *(const float4*)&Xf[(size_t)myrow * 128 + ks * 32 + q * 8];
          xb = *(const float4*)&Xf[(size_t)myrow * 128 + ks * 32 + q * 8 + 4];
        }
        union { bf16x8 v; unsigned short u[8]; } cv;
        cv.u[0] = bf16rne(xa.x); cv.u[1] = bf16rne(xa.y);
        cv.u[2] = bf16rne(xa.z); cv.u[3] = bf16rne(xa.w);
        cv.u[4] = bf16rne(xb.x); cv.u[5] = bf16rne(xb.y);
        cv.u[6] = bf16rne(xb.z); cv.u[7] = bf16rne(xb.w);
        xfrag = cv.v;
      } else {
        if (act) {
          xfrag = *(const bf16x8*)&Xh[(size_t)myrow * 128 + ks * 32 + q * 8];
        } else {
          xfrag = (bf16x8){0, 0, 0, 0, 0, 0, 0, 0};
        }
      }
      const int kchunk = ks * 4 + q;
#pragma unroll
      for (int ct = 0; ct < 8; ct++) {
        const int nn = ct * 16 + l15;
        bf16x8 wfrag = *(const bf16x8*)&Wt[nn * 128 + ((kchunk ^ (nn & 7)) << 3)];
        acc[ct] = __builtin_amdgcn_mfma_f32_16x16x32_bf16(wfrag, xfrag, acc[ct], 0, 0, 0);
      }
    }

    // epilogue: lane holds H[myrow][ct*16 + q*4 + r], r=0..3
    float ds = 0.f, dd = 0.f;
#pragma unroll
    for (int ct = 0; ct < 8; ct++) {
      const int c0 = ct * 16 + q * 4;
      float4 as4 = *(const float4*)&a_s[c0];
      float4 ad4 = *(const float4*)&a_d[c0];
      ds += acc[ct][0] * as4.x + acc[ct][1] * as4.y + acc[ct][2] * as4.z + acc[ct][3] * as4.w;
      dd += acc[ct][0] * ad4.x + acc[ct][1] * ad4.y + acc[ct][2] * ad4.z + acc[ct][3] * ad4.w;
      if (act) {
        uint2 o;
        o.x = packbf(acc[ct][0], acc[ct][1]);
        o.y = packbf(acc[ct][2], acc[ct][3]);
        *(uint2*)&H[(size_t)myrow * 128 + c0] = o;
      }
    }
    ds += __shfl_xor(ds, 16, 64);
    ds += __shfl_xor(ds, 32, 64);
    dd += __shfl_xor(dd, 16, 64);
    dd += __shfl_xor(dd, 32, 64);
    if (q == 0 && act) {
      vas[myrow] = ds;
      vad[myrow] = dd;
    }
  }
}

// ---------------- GAT aggregation: 4 nodes per wave, 16 lanes/node ----------------
// LAYER==1: relu + bf16 node output.  LAYER==2: fused mean into partial[64][128].
template <int LAYER>
__global__ __launch_bounds__(256) void gat_agg2(const unsigned short* __restrict__ H,
                                                const float* __restrict__ vas,
                                                const float* __restrict__ vad,
                                                const int* __restrict__ rowst,
                                                const int* __restrict__ esrc,
                                                const float* __restrict__ bias,
                                                unsigned short* __restrict__ OutBf,
                                                float* __restrict__ partial, int n) {
  const int tid = threadIdx.x;
  const int lane = tid & 63;
  const int wv = tid >> 6;
  const int q = lane >> 4;
  const int l = lane & 15;
  const int node = (blockIdx.x * 4 + wv) * 4 + q;  // 16 nodes per block
  const uint4* __restrict__ H4 = (const uint4*)H;

  float acc[8];
#pragma unroll
  for (int k = 0; k < 8; k++) acc[k] = 0.f;

  if (node < n) {
    const int s = rowst[node];
    const int e = rowst[node + 1];
    const int deg = e - s;
    const float adv = vad[node];
    const float eself = leaky(vas[node] + adv);
    uint4 hs = H4[(size_t)node * 16 + l];
    float wself, dsum;

    if (deg <= 16) {
      int uj = 0;
      float ej = -1e30f;
      const bool a = l < deg;
      if (a) {
        uj = esrc[s + l];
        ej = leaky(vas[uj] + adv);
      }
      float m = fmaxf(eself, ej);
#pragma unroll
      for (int o = 8; o; o >>= 1) m = fmaxf(m, __shfl_xor(m, o, 16));
      float wj = a ? __expf(ej - m) : 0.f;
      wself = __expf(eself - m);
      dsum = wj;
#pragma unroll
      for (int o = 8; o; o >>= 1) dsum += __shfl_xor(dsum, o, 16);
#pragma unroll 1
      for (int t0 = 0; t0 < deg; t0 += 4) {
        const int tb = deg - t0;
        uint4 hb[4];
        float wt[4];
#pragma unroll
        for (int i = 0; i < 4; i++) {
          if (i < tb) {
            int ut = __shfl(uj, (lane & 48) + t0 + i, 64);
            wt[i] = __shfl(wj, (lane & 48) + t0 + i, 64);
            hb[i] = H4[(size_t)ut * 16 + l];
          }
        }
#pragma unroll
        for (int i = 0; i < 4; i++)
          if (i < tb) accum8(acc, wt[i], hb[i]);
      }
    } else {
      // generic (P(deg>16) ~ 6e-5 at lambda=6)
      float m = eself;
      for (int t0 = 0; t0 < deg; t0 += 16) {
        int j = t0 + l;
        if (j < deg) {
          int u = esrc[s + j];
          m = fmaxf(m, leaky(vas[u] + adv));
        }
      }
#pragma unroll
      for (int o = 8; o; o >>= 1) m = fmaxf(m, __shfl_xor(m, o, 16));
      wself = __expf(eself - m);
      float dl = 0.f;
      for (int t0 = 0; t0 < deg; t0 += 16) {
        int j = t0 + l;
        int u2 = 0;
        float w2 = 0.f;
        if (j < deg) {
          u2 = esrc[s + j];
          w2 = __expf(leaky(vas[u2] + adv) - m);
          dl += w2;
        }
        const int cnt = min(16, deg - t0);
        for (int i0 = 0; i0 < cnt; i0 += 4) {
          const int tb = cnt - i0;
          uint4 hb[4];
          float wt[4];
#pragma unroll
          for (int i = 0; i < 4; i++) {
            if (i < tb) {
              int ut = __shfl(u2, (lane & 48) + i0 + i, 64);
              wt[i] = __shfl(w2, (lane & 48) + i0 + i, 64);
              hb[i] = H4[(size_t)ut * 16 + l];
            }
          }
#pragma unroll
          for (int i = 0; i < 4; i++)
            if (i < tb) accum8(acc, wt[i], hb[i]);
        }
      }
      dsum = dl;
#pragma unroll
      for (int o = 8; o; o >>= 1) dsum += __shfl_xor(dsum, o, 16);
    }

    // self contribution + normalize + bias
    accum8(acc, wself, hs);
    const float inv = 1.0f / (dsum + wself);
    float4 b0 = *(const float4*)&bias[8 * l];
    float4 b1v = *(const float4*)&bias[8 * l + 4];
    acc[0] = acc[0] * inv + b0.x; acc[1] = acc[1] * inv + b0.y;
    acc[2] = acc[2] * inv + b0.z; acc[3] = acc[3] * inv + b0.w;
    acc[4] = acc[4] * inv + b1v.x; acc[5] = acc[5] * inv + b1v.y;
    acc[6] = acc[6] * inv + b1v.z; acc[7] = acc[7] * inv + b1v.w;

    if (LAYER == 1) {
#pragma unroll
      for (int k = 0; k < 8; k++) acc[k] = fmaxf(acc[k], 0.f);
      uint4 o;
      o.x = packbf(acc[0], acc[1]);
      o.y = packbf(acc[2], acc[3]);
      o.z = packbf(acc[4], acc[5]);
      o.w = packbf(acc[6], acc[7]);
      ((uint4*)OutBf)[(size_t)node * 16 + l] = o;
    }
  }

  if (LAYER == 2) {
    // cross-quad sum (4 nodes of this wave); inactive quads contribute 0
#pragma unroll
    for (int k = 0; k < 8; k++) {
      acc[k] += __shfl_xor(acc[k], 16, 64);
      acc[k] += __shfl_xor(acc[k], 32, 64);
    }
    __shared__ float red[4][128];
    if (q == 0) {
#pragma unroll
      for (int k = 0; k < 8; k++) red[wv][8 * l + k] = acc[k];
    }
    __syncthreads();
    if (tid < 128) {
      float sm = red[0][tid] + red[1][tid] + red[2][tid] + red[3][tid];
      atomicAdd(&partial[(blockIdx.x & 63) * 128 + tid], sm);
    }
  }
}

// ---------------- finalize: out = sum(partial)/N ----------------
__global__ void finalize_k(const float* __restrict__ partial, float* __restrict__ out,
                           float invn) {
  int c = threadIdx.x;  // 128
  float s = 0.f;
#pragma unroll 8
  for (int r = 0; r < 64; r++) s += partial[r * 128 + c];
  out[c] = s * invn;
}

extern "C" void kernel_launch(void* const* d_in, const int* in_sizes, int n_in,
                              void* d_out, int out_size, void* d_ws, size_t ws_size,
                              hipStream_t stream) {
  const float* x = (const float*)d_in[0];
  const int* ei = (const int*)d_in[1];
  const float* W1 = (const float*)d_in[2];
  const float* a_src1 = (const float*)d_in[3];
  const float* a_dst1 = (const float*)d_in[4];
  const float* b1 = (const float*)d_in[5];
  const float* W2 = (const float*)d_in[6];
  const float* a_src2 = (const float*)d_in[7];
  const float* a_dst2 = (const float*)d_in[8];
  const float* b2 = (const float*)d_in[9];
  float* out = (float*)d_out;

  const int N = in_sizes[0] / 128;
  const int E = in_sizes[1] / 2;
  const int* src = ei;
  const int* dst = ei + E;

  const size_t rowpadded = (size_t)(N + 64) * 128;

  char* p = (char*)d_ws;
  unsigned short* B1h = (unsigned short*)p; p += rowpadded * 2;  // layer-1 agg out (bf16)
  unsigned short* Hh = (unsigned short*)p;  p += rowpadded * 2;  // per-layer GEMM out (bf16)
  float* vas = (float*)p;    p += (size_t)N * 4;
  float* vad = (float*)p;    p += (size_t)N * 4;
  int* deg = (int*)p;        p += (size_t)N * 4;
  int* rowst = (int*)p;      p += (size_t)(N + 1) * 4;
  int* fill = (int*)p;       p += (size_t)N * 4;
  int* esrc = (int*)p;       p += (size_t)E * 4;
  int* exc = (int*)p;        p += (size_t)N * 4;
  int* bsum = (int*)p;       p += 256 * 4;
  float* partial = (float*)p; p += 64 * 128 * 4;

  const int nb = (N + 1023) / 1024;  // 98 (<=128 required by scan_c2 reduce)
  const int eblocks = (E + 255) / 256;
  const int ntiles = (N + 63) / 64;
  const int aggblocks = (N + 15) / 16;  // 16 nodes per 256-thread block

  // --- CSR over dst ---
  hipMemsetAsync(deg, 0, (size_t)N * 4, stream);
  hist_kernel<<<eblocks, 256, 0, stream>>>(dst, deg, E);
  scan_a<<<nb, 256, 0, stream>>>(deg, exc, bsum, N);
  scan_c2<<<nb, 256, 0, stream>>>(exc, bsum, rowst, fill, N, E, nb);
  scatter_kernel<<<eblocks, 256, 0, stream>>>(src, dst, fill, esrc, E);

  // --- layer 1 (fp32 x read directly, cast fused) ---
  gemm_mfma<true><<<768, 256, 0, stream>>>(x, W1, a_src1, a_dst1, Hh, vas, vad, N, ntiles);
  gat_agg2<1><<<aggblocks, 256, 0, stream>>>(Hh, vas, vad, rowst, esrc, b1, B1h, nullptr, N);

  // --- layer 2 (fused mean) ---
  gemm_mfma<false><<<768, 256, 0, stream>>>(B1h, W2, a_src2, a_dst2, Hh, vas, vad, N, ntiles);
  hipMemsetAsync(partial, 0, 64 * 128 * 4, stream);
  gat_agg2<2><<<aggblocks, 256, 0, stream>>>(Hh, vas, vad, rowst, esrc, b2, nullptr, partial, N);

  // --- finalize mean ---
  finalize_k<<<1, 128, 0, stream>>>(partial, out, 1.0f / (float)N);
}